// Round 3
// baseline (776.279 us; speedup 1.0000x reference)
//
#include <hip/hip_runtime.h>
#include <hip/hip_bf16.h>

#define T_TOK 1024
#define H_DIM 1024
#define I_DIM 1408
#define NE 16
#define NEP 18   // 16 routed + 2 pseudo (shared expert = two I=1408 halves)

typedef __attribute__((ext_vector_type(8))) __bf16 bf16x8;
typedef __attribute__((ext_vector_type(4))) float f32x4;

// load 8 consecutive f32 and round to bf16x8 (for MFMA operands)
__device__ __forceinline__ bf16x8 ld8f(const float* p) {
    const float4* q = (const float4*)p;
    float4 a = q[0], b = q[1];
    bf16x8 r;
    r[0] = (__bf16)a.x; r[1] = (__bf16)a.y; r[2] = (__bf16)a.z; r[3] = (__bf16)a.w;
    r[4] = (__bf16)b.x; r[5] = (__bf16)b.y; r[6] = (__bf16)b.z; r[7] = (__bf16)b.w;
    return r;
}

// ---------------------------------------------------------------- gate ------
// 1 wave per token; full-f32 gating math so expert selection matches numpy.
__global__ __launch_bounds__(64) void gate_kernel(
    const float* __restrict__ x, const float* __restrict__ gw,
    const float* __restrict__ gb,
    int* __restrict__ counts, int* __restrict__ etok, float* __restrict__ ew)
{
    const int t = blockIdx.x;
    const int lane = threadIdx.x;
    float s[NE];
#pragma unroll
    for (int e = 0; e < NE; ++e) s[e] = 0.f;
    const float* xr = x + (size_t)t * H_DIM;
    for (int i = lane; i < H_DIM; i += 64) {
        float xv = xr[i];
#pragma unroll
        for (int e = 0; e < NE; ++e) s[e] += xv * gw[e * H_DIM + i];
    }
#pragma unroll
    for (int e = 0; e < NE; ++e) {
        for (int off = 32; off > 0; off >>= 1) s[e] += __shfl_xor(s[e], off);
    }
    if (lane == 0) {
        float scores[NE], sfc[NE];
#pragma unroll
        for (int e = 0; e < NE; ++e) {
            scores[e] = 1.f / (1.f + __expf(-s[e]));
            sfc[e] = scores[e] + gb[e];
        }
        // group score = sum of top-2 within each group of 4
        float gsc[4];
#pragma unroll
        for (int g = 0; g < 4; ++g) {
            float m1 = -1e30f, m2 = -1e30f;
#pragma unroll
            for (int j = 0; j < 4; ++j) {
                float v = sfc[4 * g + j];
                if (v > m1) { m2 = m1; m1 = v; } else if (v > m2) { m2 = v; }
            }
            gsc[g] = m1 + m2;
        }
        // top-2 groups, first-index-wins ties (matches lax.top_k)
        int g1 = 0;
        for (int g = 1; g < 4; ++g) if (gsc[g] > gsc[g1]) g1 = g;
        int g2 = -1;
        for (int g = 0; g < 4; ++g) {
            if (g == g1) continue;
            if (g2 < 0 || gsc[g] > gsc[g2]) g2 = g;
        }
        float tmp[NE];
#pragma unroll
        for (int e = 0; e < NE; ++e) {
            int gg = e >> 2;
            tmp[e] = (gg == g1 || gg == g2) ? sfc[e] : 0.0f;
        }
        int idxs[4]; float wk[4]; float wsum = 0.f;
#pragma unroll
        for (int k = 0; k < 4; ++k) {
            int bi = 0;
            for (int e = 1; e < NE; ++e) if (tmp[e] > tmp[bi]) bi = e;
            idxs[k] = bi; wk[k] = scores[bi]; wsum += scores[bi];
            tmp[bi] = -1e30f;
        }
        float inv = 1.f / (wsum + 1e-20f);
        for (int k = 0; k < 4; ++k) {
            int e = idxs[k];
            int pos = atomicAdd(&counts[e], 1);
            etok[e * T_TOK + pos] = t;
            ew[e * T_TOK + pos] = wk[k] * inv;   // SCALE = 1.0
        }
    }
}

// ---------------------------------------------------- x f32 -> bf16 ---------
__global__ __launch_bounds__(256) void cvtx_kernel(
    const float* __restrict__ x, __hip_bfloat16* __restrict__ x_bf)
{
    int i = (blockIdx.x * 256 + threadIdx.x) * 4;
    float4 v = ((const float4*)x)[i >> 2];
    x_bf[i + 0] = __float2bfloat16(v.x);
    x_bf[i + 1] = __float2bfloat16(v.y);
    x_bf[i + 2] = __float2bfloat16(v.z);
    x_bf[i + 3] = __float2bfloat16(v.w);
}

// ------------------------------------------------------------- gate/up ------
// Grid: (22, ne, 16), 256 threads. [64 tokens x 64 I-cols] tile.
__global__ __launch_bounds__(256) void gateup_kernel(
    const __hip_bfloat16* __restrict__ x_bf,
    const float* __restrict__ gproj, const float* __restrict__ uproj,
    const float* __restrict__ sgw, const float* __restrict__ suw,
    const int* __restrict__ counts, const int* __restrict__ etok,
    __hip_bfloat16* __restrict__ act, int e0)
{
    const int slot = blockIdx.y;
    const int e = e0 + slot;
    const int cnt = (e < NE) ? counts[e] : T_TOK;
    const int row0 = blockIdx.z * 64;
    if (row0 >= cnt) return;              // down also skips these tiles
    __shared__ int toks[64];
    if (threadIdx.x < 64) {
        int r = row0 + threadIdx.x;
        toks[threadIdx.x] = (e < NE) ? ((r < cnt) ? etok[e * T_TOK + r] : 0) : r;
    }
    __syncthreads();
    const int lane = threadIdx.x & 63;
    const int wv = threadIdx.x >> 6;
    const int col = lane & 15, kq = lane >> 4;
    const int nb = blockIdx.x * 64 + wv * 16;
    const float *wg, *wu;
    if (e < NE) {
        wg = gproj + (size_t)e * I_DIM * H_DIM;
        wu = uproj + (size_t)e * I_DIM * H_DIM;
    } else {
        wg = sgw + (size_t)(e - NE) * I_DIM * H_DIM;
        wu = suw + (size_t)(e - NE) * I_DIM * H_DIM;
    }
    const float* bg = wg + (size_t)(nb + col) * H_DIM + kq * 8;
    const float* bu = wu + (size_t)(nb + col) * H_DIM + kq * 8;
    const __hip_bfloat16* ar[4];
#pragma unroll
    for (int mi = 0; mi < 4; ++mi)
        ar[mi] = x_bf + (size_t)toks[mi * 16 + col] * H_DIM + kq * 8;
    f32x4 accg[4], accu[4];
#pragma unroll
    for (int mi = 0; mi < 4; ++mi) {
        accg[mi] = (f32x4){0.f, 0.f, 0.f, 0.f};
        accu[mi] = (f32x4){0.f, 0.f, 0.f, 0.f};
    }
    for (int k = 0; k < H_DIM / 32; ++k) {
        bf16x8 bgv = ld8f(bg + k * 32);
        bf16x8 buv = ld8f(bu + k * 32);
#pragma unroll
        for (int mi = 0; mi < 4; ++mi) {
            bf16x8 av = *(const bf16x8*)(ar[mi] + k * 32);
            accg[mi] = __builtin_amdgcn_mfma_f32_16x16x32_bf16(av, bgv, accg[mi], 0, 0, 0);
            accu[mi] = __builtin_amdgcn_mfma_f32_16x16x32_bf16(av, buv, accu[mi], 0, 0, 0);
        }
    }
#pragma unroll
    for (int mi = 0; mi < 4; ++mi) {
#pragma unroll
        for (int r = 0; r < 4; ++r) {
            int grow = row0 + mi * 16 + kq * 4 + r;
            float g = accg[mi][r];
            // rows >= cnt inside a partial tile are zero-padded (down reads them)
            float a = (grow < cnt) ? (g / (1.f + __expf(-g)) * accu[mi][r]) : 0.f;
            if (grow < T_TOK)
                act[((size_t)slot * T_TOK + grow) * I_DIM + nb + col] = __float2bfloat16(a);
        }
    }
}

// ---------------------------------------------------------------- down ------
// Grid: (16, ne, 16), 256 threads. Weighted atomicAdd directly into f32 out.
__global__ __launch_bounds__(256) void down_kernel(
    const __hip_bfloat16* __restrict__ act,
    const float* __restrict__ dproj, const float* __restrict__ sdw,
    const int* __restrict__ counts, const int* __restrict__ etok,
    const float* __restrict__ ew, float* __restrict__ y, int e0)
{
    const int slot = blockIdx.y;
    const int e = e0 + slot;
    const int cnt = (e < NE) ? counts[e] : T_TOK;
    const int row0 = blockIdx.z * 64;
    if (row0 >= cnt) return;
    __shared__ int toks[64];
    __shared__ float wts[64];
    if (threadIdx.x < 64) {
        int r = row0 + threadIdx.x;
        if (e < NE) {
            bool ok = r < cnt;
            toks[threadIdx.x] = ok ? etok[e * T_TOK + r] : 0;
            wts[threadIdx.x]  = ok ? ew[e * T_TOK + r] : 0.f;
        } else { toks[threadIdx.x] = r; wts[threadIdx.x] = 1.f; }
    }
    __syncthreads();
    const int lane = threadIdx.x & 63;
    const int wv = threadIdx.x >> 6;
    const int col = lane & 15, kq = lane >> 4;
    const int nb = blockIdx.x * 64 + wv * 16;   // H column
    const float* wd;
    int wstride;
    if (e < NE) { wd = dproj + (size_t)e * H_DIM * I_DIM; wstride = I_DIM; }
    else        { wd = sdw + (size_t)(e - NE) * I_DIM;    wstride = 2 * I_DIM; }
    const float* bp = wd + (size_t)(nb + col) * wstride + kq * 8;
    const __hip_bfloat16* ar[4];
#pragma unroll
    for (int mi = 0; mi < 4; ++mi)
        ar[mi] = act + ((size_t)slot * T_TOK + row0 + mi * 16 + col) * I_DIM + kq * 8;
    f32x4 acc[4];
#pragma unroll
    for (int mi = 0; mi < 4; ++mi) acc[mi] = (f32x4){0.f, 0.f, 0.f, 0.f};
    for (int k = 0; k < I_DIM / 32; ++k) {
        bf16x8 bv = ld8f(bp + k * 32);
#pragma unroll
        for (int mi = 0; mi < 4; ++mi) {
            bf16x8 av = *(const bf16x8*)(ar[mi] + k * 32);
            acc[mi] = __builtin_amdgcn_mfma_f32_16x16x32_bf16(av, bv, acc[mi], 0, 0, 0);
        }
    }
#pragma unroll
    for (int mi = 0; mi < 4; ++mi) {
#pragma unroll
        for (int r = 0; r < 4; ++r) {
            int lr = mi * 16 + kq * 4 + r;
            int grow = row0 + lr;
            if (grow < cnt)
                atomicAdd(&y[(size_t)toks[lr] * H_DIM + nb + col], acc[mi][r] * wts[lr]);
        }
    }
}

// -------------------------------------------------------------- launch ------
extern "C" void kernel_launch(void* const* d_in, const int* in_sizes, int n_in,
                              void* d_out, int out_size, void* d_ws, size_t ws_size,
                              hipStream_t stream) {
    (void)in_sizes; (void)n_in; (void)out_size;
    const float* x  = (const float*)d_in[0];
    const float* gw = (const float*)d_in[1];
    const float* gb = (const float*)d_in[2];
    const float* gp = (const float*)d_in[3];
    const float* up = (const float*)d_in[4];
    const float* dp = (const float*)d_in[5];
    const float* sg = (const float*)d_in[6];
    const float* su = (const float*)d_in[7];
    const float* sd = (const float*)d_in[8];
    float* out = (float*)d_out;

    char* ws = (char*)d_ws;
    int*   counts = (int*)ws;                                    // @0      (64 B)
    int*   etok   = (int*)(ws + 256);                            // @256    (64 KB)
    float* ew     = (float*)(ws + 256 + 65536);                  // @65792  (64 KB)
    __hip_bfloat16* x_bf = (__hip_bfloat16*)(ws + 131328);       // 2 MB
    __hip_bfloat16* act  = (__hip_bfloat16*)(ws + 2228480);      // up to ~52 MB

    // expert chunking if workspace is small
    size_t fixed = 2228480;
    size_t per_e = (size_t)T_TOK * I_DIM * 2;                    // 2.75 MB / slot
    int cap = NEP;
    if (ws_size < fixed + (size_t)NEP * per_e) {
        cap = (ws_size > fixed + per_e) ? (int)((ws_size - fixed) / per_e) : 1;
        if (cap < 1) cap = 1;
    }

    hipMemsetAsync(ws, 0, 256, stream);                          // counts
    hipMemsetAsync(out, 0, (size_t)T_TOK * H_DIM * 4, stream);   // harness poisons d_out

    gate_kernel<<<dim3(T_TOK), dim3(64), 0, stream>>>(x, gw, gb, counts, etok, ew);
    cvtx_kernel<<<dim3(1024), dim3(256), 0, stream>>>(x, x_bf);

    for (int e0 = 0; e0 < NEP; e0 += cap) {
        int ne = NEP - e0 < cap ? NEP - e0 : cap;
        gateup_kernel<<<dim3(22, ne, 16), dim3(256), 0, stream>>>(
            x_bf, gp, up, sg, su, counts, etok, act, e0);
        down_kernel<<<dim3(16, ne, 16), dim3(256), 0, stream>>>(
            act, dp, sd, counts, etok, ew, out, e0);
    }
}

// Round 4
// 536.617 us; speedup vs baseline: 1.4466x; 1.4466x over previous
//
#include <hip/hip_runtime.h>
#include <hip/hip_bf16.h>

#define T_TOK 1024
#define H_DIM 1024
#define I_DIM 1408
#define NE 16
#define NEP 18   // 16 routed + 2 pseudo (shared expert = two I=1408 halves)
#define BM 256   // token tile per block
#define LDB 40   // padded LDS row (32 K bf16 + 8 pad) -> 2-way bank alias only

typedef __attribute__((ext_vector_type(8))) __bf16 bf16x8;
typedef __attribute__((ext_vector_type(4))) float f32x4;

__device__ __forceinline__ bf16x8 cvt8(float4 a, float4 b) {
    bf16x8 r;
    r[0] = (__bf16)a.x; r[1] = (__bf16)a.y; r[2] = (__bf16)a.z; r[3] = (__bf16)a.w;
    r[4] = (__bf16)b.x; r[5] = (__bf16)b.y; r[6] = (__bf16)b.z; r[7] = (__bf16)b.w;
    return r;
}

// ---------------------------------------------------------------- gate ------
__global__ __launch_bounds__(64) void gate_kernel(
    const float* __restrict__ x, const float* __restrict__ gw,
    const float* __restrict__ gb,
    int* __restrict__ counts, int* __restrict__ etok, float* __restrict__ ew)
{
    const int t = blockIdx.x;
    const int lane = threadIdx.x;
    float s[NE];
#pragma unroll
    for (int e = 0; e < NE; ++e) s[e] = 0.f;
    const float* xr = x + (size_t)t * H_DIM;
    for (int i = lane; i < H_DIM; i += 64) {
        float xv = xr[i];
#pragma unroll
        for (int e = 0; e < NE; ++e) s[e] += xv * gw[e * H_DIM + i];
    }
#pragma unroll
    for (int e = 0; e < NE; ++e) {
        for (int off = 32; off > 0; off >>= 1) s[e] += __shfl_xor(s[e], off);
    }
    if (lane == 0) {
        float scores[NE], sfc[NE];
#pragma unroll
        for (int e = 0; e < NE; ++e) {
            scores[e] = 1.f / (1.f + __expf(-s[e]));
            sfc[e] = scores[e] + gb[e];
        }
        float gsc[4];
#pragma unroll
        for (int g = 0; g < 4; ++g) {
            float m1 = -1e30f, m2 = -1e30f;
#pragma unroll
            for (int j = 0; j < 4; ++j) {
                float v = sfc[4 * g + j];
                if (v > m1) { m2 = m1; m1 = v; } else if (v > m2) { m2 = v; }
            }
            gsc[g] = m1 + m2;
        }
        int g1 = 0;
        for (int g = 1; g < 4; ++g) if (gsc[g] > gsc[g1]) g1 = g;
        int g2 = -1;
        for (int g = 0; g < 4; ++g) {
            if (g == g1) continue;
            if (g2 < 0 || gsc[g] > gsc[g2]) g2 = g;
        }
        float tmp[NE];
#pragma unroll
        for (int e = 0; e < NE; ++e) {
            int gg = e >> 2;
            tmp[e] = (gg == g1 || gg == g2) ? sfc[e] : 0.0f;
        }
        int idxs[4]; float wk[4]; float wsum = 0.f;
#pragma unroll
        for (int k = 0; k < 4; ++k) {
            int bi = 0;
            for (int e = 1; e < NE; ++e) if (tmp[e] > tmp[bi]) bi = e;
            idxs[k] = bi; wk[k] = scores[bi]; wsum += scores[bi];
            tmp[bi] = -1e30f;
        }
        float inv = 1.f / (wsum + 1e-20f);
        for (int k = 0; k < 4; ++k) {
            int e = idxs[k];
            int pos = atomicAdd(&counts[e], 1);
            etok[e * T_TOK + pos] = t;
            ew[e * T_TOK + pos] = wk[k] * inv;   // SCALE = 1.0
        }
    }
}

// ---------------------------------------------------- x f32 -> bf16 ---------
__global__ __launch_bounds__(256) void cvtx_kernel(
    const float* __restrict__ x, __hip_bfloat16* __restrict__ x_bf)
{
    int i = (blockIdx.x * 256 + threadIdx.x) * 4;
    float4 v = ((const float4*)x)[i >> 2];
    x_bf[i + 0] = __float2bfloat16(v.x);
    x_bf[i + 1] = __float2bfloat16(v.y);
    x_bf[i + 2] = __float2bfloat16(v.z);
    x_bf[i + 3] = __float2bfloat16(v.w);
}

// ------------------------------------------------------------- gate/up ------
// Grid (22, ne, 4). Block = [BM=256 tok x 64 I-cols]; wave w owns 64 tokens.
// B (gate+up weight K-slices) double-buffered in LDS as bf16; f32 loads for
// k+1 issued before compute(k); cvt+ds_write after MFMAs.
__global__ __launch_bounds__(256, 2) void gateup_kernel(
    const __hip_bfloat16* __restrict__ x_bf,
    const float* __restrict__ gproj, const float* __restrict__ uproj,
    const float* __restrict__ sgw, const float* __restrict__ suw,
    const int* __restrict__ counts, const int* __restrict__ etok,
    __hip_bfloat16* __restrict__ act, int e0)
{
    const int slot = blockIdx.y;
    const int e = e0 + slot;
    const int cnt = (e < NE) ? counts[e] : T_TOK;
    const int row0 = blockIdx.z * BM;
    if (row0 >= cnt) return;

    __shared__ int toks[BM];
    __shared__ __hip_bfloat16 Bg[2][64 * LDB];
    __shared__ __hip_bfloat16 Bu[2][64 * LDB];

    const int tid = threadIdx.x;
    {
        int r = row0 + tid;
        toks[tid] = (e < NE) ? ((r < cnt) ? etok[e * T_TOK + r] : 0) : r;
    }

    const int nb0 = blockIdx.x * 64;
    const float *wg, *wu;
    if (e < NE) {
        wg = gproj + (size_t)e * I_DIM * H_DIM;
        wu = uproj + (size_t)e * I_DIM * H_DIM;
    } else {
        wg = sgw + (size_t)(e - NE) * I_DIM * H_DIM;
        wu = suw + (size_t)(e - NE) * I_DIM * H_DIM;
    }
    // staging: thread -> (scol = tid>>2, sq = tid&3), 8 f32 each
    const int scol = tid >> 2, sq = tid & 3;
    const float* sgp = wg + (size_t)(nb0 + scol) * H_DIM + sq * 8;
    const float* sup = wu + (size_t)(nb0 + scol) * H_DIM + sq * 8;
    const int lws = scol * LDB + sq * 8;   // lds write offset (bf16 elems)

    const int lane = tid & 63;
    const int w = tid >> 6;
    const int col = lane & 15, kq = lane >> 4;

    __syncthreads();   // toks visible

    const __hip_bfloat16* ar[4];
#pragma unroll
    for (int mi = 0; mi < 4; ++mi)
        ar[mi] = x_bf + (size_t)toks[w * 64 + mi * 16 + col] * H_DIM + kq * 8;

    f32x4 accg[4][4], accu[4][4];
#pragma unroll
    for (int mi = 0; mi < 4; ++mi)
#pragma unroll
        for (int ni = 0; ni < 4; ++ni) {
            accg[mi][ni] = (f32x4){0.f, 0.f, 0.f, 0.f};
            accu[mi][ni] = (f32x4){0.f, 0.f, 0.f, 0.f};
        }

    // prologue loads for k=0
    float4 ga = ((const float4*)sgp)[0], gb4 = ((const float4*)sgp)[1];
    float4 ua = ((const float4*)sup)[0], ub = ((const float4*)sup)[1];

    for (int k = 0; k < 32; ++k) {
        const int buf = k & 1;
        // write staged regs (loaded last iter / prologue) into LDS
        *(bf16x8*)&Bg[buf][lws] = cvt8(ga, gb4);
        *(bf16x8*)&Bu[buf][lws] = cvt8(ua, ub);
        __syncthreads();
        if (k < 31) {   // issue next K-slice loads; consumed next iteration
            const float* pg = sgp + (k + 1) * 32;
            const float* pu = sup + (k + 1) * 32;
            ga = ((const float4*)pg)[0]; gb4 = ((const float4*)pg)[1];
            ua = ((const float4*)pu)[0]; ub = ((const float4*)pu)[1];
        }
        bf16x8 a[4], bg[4], bu[4];
#pragma unroll
        for (int mi = 0; mi < 4; ++mi) a[mi] = *(const bf16x8*)(ar[mi] + k * 32);
#pragma unroll
        for (int ni = 0; ni < 4; ++ni) {
            bg[ni] = *(const bf16x8*)&Bg[buf][(ni * 16 + col) * LDB + kq * 8];
            bu[ni] = *(const bf16x8*)&Bu[buf][(ni * 16 + col) * LDB + kq * 8];
        }
#pragma unroll
        for (int mi = 0; mi < 4; ++mi)
#pragma unroll
            for (int ni = 0; ni < 4; ++ni) {
                accg[mi][ni] = __builtin_amdgcn_mfma_f32_16x16x32_bf16(a[mi], bg[ni], accg[mi][ni], 0, 0, 0);
                accu[mi][ni] = __builtin_amdgcn_mfma_f32_16x16x32_bf16(a[mi], bu[ni], accu[mi][ni], 0, 0, 0);
            }
        __syncthreads();   // all reads of buf done before it's overwritten
    }

    // epilogue: silu(g)*u -> act (zeros for padded rows so down reads zeros)
#pragma unroll
    for (int mi = 0; mi < 4; ++mi)
#pragma unroll
        for (int ni = 0; ni < 4; ++ni)
#pragma unroll
            for (int r = 0; r < 4; ++r) {
                int lrow = w * 64 + mi * 16 + kq * 4 + r;
                int grow = row0 + lrow;
                float g = accg[mi][ni][r];
                float a = (grow < cnt) ? (g / (1.f + __expf(-g)) * accu[mi][ni][r]) : 0.f;
                act[((size_t)slot * T_TOK + grow) * I_DIM + nb0 + ni * 16 + col] =
                    __float2bfloat16(a);
            }
}

// ---------------------------------------------------------------- down ------
// Grid (16, ne, 4). Block = [BM=256 act-rows x 64 H-cols]; K = I_DIM = 44*32.
__global__ __launch_bounds__(256, 2) void down_kernel(
    const __hip_bfloat16* __restrict__ act,
    const float* __restrict__ dproj, const float* __restrict__ sdw,
    const int* __restrict__ counts, const int* __restrict__ etok,
    const float* __restrict__ ew, float* __restrict__ y, int e0)
{
    const int slot = blockIdx.y;
    const int e = e0 + slot;
    const int cnt = (e < NE) ? counts[e] : T_TOK;
    const int row0 = blockIdx.z * BM;
    if (row0 >= cnt) return;

    __shared__ int toks[BM];
    __shared__ float wts[BM];
    __shared__ __hip_bfloat16 Bd[2][64 * LDB];

    const int tid = threadIdx.x;
    {
        int r = row0 + tid;
        if (e < NE) {
            bool ok = r < cnt;
            toks[tid] = ok ? etok[e * T_TOK + r] : 0;
            wts[tid]  = ok ? ew[e * T_TOK + r] : 0.f;
        } else { toks[tid] = r; wts[tid] = 1.f; }
    }

    const int nb0 = blockIdx.x * 64;
    const float* wd;
    int wstride;
    if (e < NE) { wd = dproj + (size_t)e * H_DIM * I_DIM; wstride = I_DIM; }
    else        { wd = sdw + (size_t)(e - NE) * I_DIM;    wstride = 2 * I_DIM; }
    const int scol = tid >> 2, sq = tid & 3;
    const float* sdp = wd + (size_t)(nb0 + scol) * wstride + sq * 8;
    const int lws = scol * LDB + sq * 8;

    const int lane = tid & 63;
    const int w = tid >> 6;
    const int col = lane & 15, kq = lane >> 4;

    __syncthreads();

    const __hip_bfloat16* ar[4];
#pragma unroll
    for (int mi = 0; mi < 4; ++mi)
        ar[mi] = act + ((size_t)slot * T_TOK + row0 + w * 64 + mi * 16 + col) * I_DIM + kq * 8;

    f32x4 acc[4][4];
#pragma unroll
    for (int mi = 0; mi < 4; ++mi)
#pragma unroll
        for (int ni = 0; ni < 4; ++ni) acc[mi][ni] = (f32x4){0.f, 0.f, 0.f, 0.f};

    float4 da = ((const float4*)sdp)[0], db = ((const float4*)sdp)[1];

    for (int k = 0; k < I_DIM / 32; ++k) {
        const int buf = k & 1;
        *(bf16x8*)&Bd[buf][lws] = cvt8(da, db);
        __syncthreads();
        if (k < I_DIM / 32 - 1) {
            const float* pd = sdp + (k + 1) * 32;
            da = ((const float4*)pd)[0]; db = ((const float4*)pd)[1];
        }
        bf16x8 a[4], b[4];
#pragma unroll
        for (int mi = 0; mi < 4; ++mi) a[mi] = *(const bf16x8*)(ar[mi] + k * 32);
#pragma unroll
        for (int ni = 0; ni < 4; ++ni)
            b[ni] = *(const bf16x8*)&Bd[buf][(ni * 16 + col) * LDB + kq * 8];
#pragma unroll
        for (int mi = 0; mi < 4; ++mi)
#pragma unroll
            for (int ni = 0; ni < 4; ++ni)
                acc[mi][ni] = __builtin_amdgcn_mfma_f32_16x16x32_bf16(a[mi], b[ni], acc[mi][ni], 0, 0, 0);
        __syncthreads();
    }

#pragma unroll
    for (int mi = 0; mi < 4; ++mi)
#pragma unroll
        for (int ni = 0; ni < 4; ++ni)
#pragma unroll
            for (int r = 0; r < 4; ++r) {
                int lrow = w * 64 + mi * 16 + kq * 4 + r;
                int grow = row0 + lrow;
                if (grow < cnt)
                    atomicAdd(&y[(size_t)toks[lrow] * H_DIM + nb0 + ni * 16 + col],
                              acc[mi][ni][r] * wts[lrow]);
            }
}

// -------------------------------------------------------------- launch ------
extern "C" void kernel_launch(void* const* d_in, const int* in_sizes, int n_in,
                              void* d_out, int out_size, void* d_ws, size_t ws_size,
                              hipStream_t stream) {
    (void)in_sizes; (void)n_in; (void)out_size;
    const float* x  = (const float*)d_in[0];
    const float* gw = (const float*)d_in[1];
    const float* gb = (const float*)d_in[2];
    const float* gp = (const float*)d_in[3];
    const float* up = (const float*)d_in[4];
    const float* dp = (const float*)d_in[5];
    const float* sg = (const float*)d_in[6];
    const float* su = (const float*)d_in[7];
    const float* sd = (const float*)d_in[8];
    float* out = (float*)d_out;

    char* ws = (char*)d_ws;
    int*   counts = (int*)ws;                                    // @0      (64 B)
    int*   etok   = (int*)(ws + 256);                            // 64 KB
    float* ew     = (float*)(ws + 256 + 65536);                  // 64 KB
    __hip_bfloat16* x_bf = (__hip_bfloat16*)(ws + 131328);       // 2 MB
    __hip_bfloat16* act  = (__hip_bfloat16*)(ws + 2228480);      // up to ~52 MB

    size_t fixed = 2228480;
    size_t per_e = (size_t)T_TOK * I_DIM * 2;                    // 2.75 MB / slot
    int cap = NEP;
    if (ws_size < fixed + (size_t)NEP * per_e) {
        cap = (ws_size > fixed + per_e) ? (int)((ws_size - fixed) / per_e) : 1;
        if (cap < 1) cap = 1;
    }

    hipMemsetAsync(ws, 0, 256, stream);                          // counts
    hipMemsetAsync(out, 0, (size_t)T_TOK * H_DIM * 4, stream);   // d_out is poisoned

    gate_kernel<<<dim3(T_TOK), dim3(64), 0, stream>>>(x, gw, gb, counts, etok, ew);
    cvtx_kernel<<<dim3(1024), dim3(256), 0, stream>>>(x, x_bf);

    for (int e0 = 0; e0 < NEP; e0 += cap) {
        int ne = NEP - e0 < cap ? NEP - e0 : cap;
        gateup_kernel<<<dim3(I_DIM / 64, ne, T_TOK / BM), dim3(256), 0, stream>>>(
            x_bf, gp, up, sg, su, counts, etok, act, e0);
        down_kernel<<<dim3(H_DIM / 64, ne, T_TOK / BM), dim3(256), 0, stream>>>(
            act, dp, sd, counts, etok, ew, out, e0);
    }
}